// Round 9
// baseline (14.736 us; speedup 1.0000x reference)
//
#include <hip/hip_runtime.h>
#include <math.h>

#define GN 512
#define GB 2
#define INCH 128
#define GD 64
#define ALPHA 0.2f
#define NEG_INF_F (-9e15f)

typedef float f32x4 __attribute__((ext_vector_type(4)));
typedef short short8 __attribute__((ext_vector_type(8)));

__device__ __forceinline__ unsigned f2bf(float f) {  // RNE f32->bf16 bits
    unsigned u = __float_as_uint(f);
    return (u + 0x7FFFu + ((u >> 16) & 1u)) >> 16;
}

// K1 (MFMA): hidden^T(bf16) = (x @ W)^T, s1 = a[0:64]·h, s2 = a[64:128]·h.
// 64 blocks x 256 threads; block owns 16 rows; wave w owns d-cols [w*16,w*16+16).
// W staged transposed+bf16+chunk-XOR-swizzled in LDS; A-frags direct from x.
// h_T[d][flatrow] layout = MFMA-B layout for K2's PV.
__global__ __launch_bounds__(256) void k_hidden(
        const float* __restrict__ x, const float* __restrict__ W,
        const float* __restrict__ a,
        unsigned short* __restrict__ hT, float* __restrict__ s1,
        float* __restrict__ s2) {
    const int blk = blockIdx.x;      // 0..63
    const int row0 = blk * 16;
    const int tid = threadIdx.x;
    const int lane = tid & 63;
    const int w = tid >> 6;          // 0..3
    const int lane15 = lane & 15;
    const int kg = lane >> 4;        // 0..3
    __shared__ char WtB[GD * 256];   // Wt bf16 [64 d][128 k], swizzled, 16 KB
    __shared__ float sp1[4][16], sp2[4][16];

    // stage W -> Wt: coalesced column reads (consecutive lanes = consecutive d)
    #pragma unroll
    for (int t = 0; t < 8; ++t) {
        const int idx = tid + t * 256;        // 0..2047
        const int d = idx & 63;
        const int kq = idx >> 6;              // k-quad 0..31
        unsigned short q[4];
        #pragma unroll
        for (int e = 0; e < 4; ++e)
            q[e] = (unsigned short)f2bf(W[(kq * 4 + e) * GD + d]);
        const int byte = d * 256 + (((kq >> 1) ^ (d & 7)) << 4) + (kq & 1) * 8;
        uint2 pk;
        pk.x = (unsigned)q[0] | ((unsigned)q[1] << 16);
        pk.y = (unsigned)q[2] | ((unsigned)q[3] << 16);
        *(uint2*)(WtB + byte) = pk;
    }
    const int dcol = w * 16 + lane15;
    const float a1 = a[dcol], a2 = a[GD + dcol];
    __syncthreads();

    f32x4 acc = (f32x4)0.f;
    #pragma unroll
    for (int kt = 0; kt < 4; ++kt) {
        const float* px = x + (size_t)(row0 + lane15) * INCH + kt * 32 + kg * 8;
        const float4 lo = *(const float4*)px;
        const float4 hi = *(const float4*)(px + 4);
        int4 ai;
        ai.x = f2bf(lo.x) | (f2bf(lo.y) << 16);
        ai.y = f2bf(lo.z) | (f2bf(lo.w) << 16);
        ai.z = f2bf(hi.x) | (f2bf(hi.y) << 16);
        ai.w = f2bf(hi.z) | (f2bf(hi.w) << 16);
        const short8 av = __builtin_bit_cast(short8, ai);
        const short8 bv = *(const short8*)(WtB + dcol * 256 +
                              (((kt * 4 + kg) ^ (dcol & 7)) << 4));
        acc = __builtin_amdgcn_mfma_f32_16x16x32_bf16(av, bv, acc, 0, 0, 0);
    }
    // h_T store: rows row0+kg*4..+3 at column dcol (packed ushort4 = 8B)
    uint2 hw;
    hw.x = f2bf(acc[0]) | (f2bf(acc[1]) << 16);
    hw.y = f2bf(acc[2]) | (f2bf(acc[3]) << 16);
    *(uint2*)(hT + (size_t)dcol * (GB * GN) + row0 + kg * 4) = hw;
    // s1/s2 partials: reduce over this wave's 16 d-cols, per row kg*4+r
    #pragma unroll
    for (int r = 0; r < 4; ++r) {
        float t1 = acc[r] * a1, t2 = acc[r] * a2;
        #pragma unroll
        for (int off = 1; off < 16; off <<= 1) {
            t1 += __shfl_xor(t1, off, 64);
            t2 += __shfl_xor(t2, off, 64);
        }
        if (lane15 == 0) { sp1[w][kg * 4 + r] = t1; sp2[w][kg * 4 + r] = t2; }
    }
    __syncthreads();
    if (tid < 16) {
        s1[row0 + tid] = sp1[0][tid] + sp1[1][tid] + sp1[2][tid] + sp1[3][tid];
        s2[row0 + tid] = sp2[0][tid] + sp2[1][tid] + sp2[2][tid] + sp2[3][tid];
    }
}

// K2: per (b,i): closed-form logits (validated r1-r8) -> masked leaky-relu ->
// softmax (normalized, bf16, swizzled A-tile in LDS) -> PV via MFMA + bias.
//   i < 256 : pre(j) = (s1+s2)[2i + (j>=256)]
//   i >= 256: pre(j) = s1[2*(j%256)] + s2[2*(j%256)+1]   (period 4 in seg)
// 128 blocks x 512 threads; TI=8 rows/block; wave w owns softmax row i0+w AND
// PV K-slice j in [w*64,w*64+64). B-frags (h_T) preissued before the softmax
// barrier (T14). Cross-wave K-reduce via padded LDS.
__global__ __launch_bounds__(512) void k_attn(
        const int* __restrict__ adj, const unsigned short* __restrict__ hT,
        const float* __restrict__ s1, const float* __restrict__ s2,
        const float* __restrict__ bias, float* __restrict__ out) {
    const int blk = blockIdx.x;       // 0..127
    const int b = blk >> 6;
    const int i0 = (blk & 63) * 8;
    const int tid = threadIdx.x;
    const int lane = tid & 63;
    const int w = tid >> 6;           // 0..7
    const int lane15 = lane & 15;
    const int kg = lane >> 4;

    __shared__ unsigned short pbf[16 * GN];   // A-tile bf16, swizzled, 16 KB
    __shared__ float red[8 * GD * 9];         // [w][d][r pad 9], 18 KB

    // ---- preissue B-frags (independent of softmax) ----
    short8 bv[2][4];
    #pragma unroll
    for (int ktl = 0; ktl < 2; ++ktl) {
        const int kbase = w * 64 + ktl * 32;
        #pragma unroll
        for (int ct = 0; ct < 4; ++ct)
            bv[ktl][ct] = *(const short8*)(hT +
                (size_t)(ct * 16 + lane15) * (GB * GN) + b * GN + kbase + kg * 8);
    }
    // zero A rows 8..15 (garbage rows; their C rows are discarded but keep clean)
    ((uint4*)(pbf + 8 * GN))[tid] = make_uint4(0, 0, 0, 0);

    // ---- softmax: wave w owns row i0+w ----
    {
        const int i = i0 + w;
        const int* adjw = adj + ((size_t)b * GN + i) * GN;
        const float* s1b = s1 + b * GN;
        const float* s2b = s2 + b * GN;
        float v[8];
        if (i < 256) {
            float c0 = s1b[2 * i] + s2b[2 * i];
            float c1 = s1b[2 * i + 1] + s2b[2 * i + 1];
            c0 = c0 >= 0.f ? c0 : ALPHA * c0;
            c1 = c1 >= 0.f ? c1 : ALPHA * c1;
            #pragma unroll
            for (int seg = 0; seg < 8; ++seg)
                v[seg] = adjw[seg * 64 + lane] > 0 ? (seg < 4 ? c0 : c1) : NEG_INF_F;
        } else {
            float pre4[4];
            #pragma unroll
            for (int sg = 0; sg < 4; ++sg) {          // m has period 4 in seg
                const int m = (sg * 64 + lane) & 255;
                float pre = s1b[2 * m] + s2b[2 * m + 1];
                pre4[sg] = pre >= 0.f ? pre : ALPHA * pre;
            }
            #pragma unroll
            for (int seg = 0; seg < 8; ++seg)
                v[seg] = adjw[seg * 64 + lane] > 0 ? pre4[seg & 3] : NEG_INF_F;
        }
        float mx = v[0];
        #pragma unroll
        for (int seg = 1; seg < 8; ++seg) mx = fmaxf(mx, v[seg]);
        #pragma unroll
        for (int off = 32; off > 0; off >>= 1) mx = fmaxf(mx, __shfl_xor(mx, off, 64));
        float e[8], s = 0.f;
        #pragma unroll
        for (int seg = 0; seg < 8; ++seg) {
            e[seg] = __expf(v[seg] - mx);
            s += e[seg];
        }
        #pragma unroll
        for (int off = 32; off > 0; off >>= 1) s += __shfl_xor(s, off, 64);
        const float inv = 1.f / s;
        #pragma unroll
        for (int seg = 0; seg < 8; ++seg) {           // bf16, chunk-XOR swizzle
            const int j = seg * 64 + lane;
            const int byte = w * 1024 + (((j >> 3) ^ (w & 7)) << 4) + (j & 7) * 2;
            *(unsigned short*)((char*)pbf + byte) = (unsigned short)f2bf(e[seg] * inv);
        }
    }
    __syncthreads();

    // ---- PV via MFMA: A rows = block's 8 i-rows (pad 16), K-slice per wave ----
    f32x4 acc[4];
    #pragma unroll
    for (int ct = 0; ct < 4; ++ct) acc[ct] = (f32x4)0.f;
    #pragma unroll
    for (int ktl = 0; ktl < 2; ++ktl) {
        const int kbase = w * 64 + ktl * 32;
        const short8 av = *(const short8*)((char*)pbf + lane15 * 1024 +
                              ((((kbase >> 3) + kg) ^ (lane15 & 7)) << 4));
        #pragma unroll
        for (int ct = 0; ct < 4; ++ct)
            acc[ct] = __builtin_amdgcn_mfma_f32_16x16x32_bf16(
                          av, bv[ktl][ct], acc[ct], 0, 0, 0);
    }
    if (kg < 2) {       // C rows 0..7 live in kg 0/1 (row = kg*4+r)
        #pragma unroll
        for (int ct = 0; ct < 4; ++ct)
            #pragma unroll
            for (int r = 0; r < 4; ++r)
                red[(w * GD + ct * 16 + lane15) * 9 + kg * 4 + r] = acc[ct][r];
    }
    __syncthreads();

    {
        const int r = tid >> 6, d = tid & 63;         // 8 rows x 64 d = 512
        float o = 0.f;
        #pragma unroll
        for (int ww = 0; ww < 8; ++ww) o += red[(ww * GD + d) * 9 + r];
        out[((size_t)b * GN + i0 + r) * GD + d] = o + bias[d];
    }
}

extern "C" void kernel_launch(void* const* d_in, const int* in_sizes, int n_in,
                              void* d_out, int out_size, void* d_ws, size_t ws_size,
                              hipStream_t stream) {
    const float* x    = (const float*)d_in[0];
    const int*   adj  = (const int*)d_in[1];
    const float* W    = (const float*)d_in[2];
    const float* a    = (const float*)d_in[3];
    const float* bias = (const float*)d_in[4];
    float* out = (float*)d_out;

    // ws layout: hT ushort[64][1024] (128 KB) | s1 f32[1024] | s2 f32[1024]
    unsigned short* hT = (unsigned short*)d_ws;
    float* s1f = (float*)((char*)d_ws + GD * GB * GN * sizeof(unsigned short));
    float* s2f = s1f + GB * GN;

    k_hidden<<<GB * GN / 16, 256, 0, stream>>>(x, W, a, hT, s1f, s2f);
    k_attn<<<GB * GN / 8, 512, 0, stream>>>(adj, hT, s1f, s2f, bias, out);
}

// Round 10
// 14.295 us; speedup vs baseline: 1.0308x; 1.0308x over previous
//
#include <hip/hip_runtime.h>
#include <math.h>

#define GN 512
#define GB 2
#define INCH 128
#define GD 64
#define ALPHA 0.2f
#define NEG_INF_F (-9e15f)
#define TI 4   // attention rows per k_attn block

__device__ __forceinline__ unsigned f2bf(float f) {  // RNE f32->bf16 bits
    unsigned u = __float_as_uint(f);
    return (u + 0x7FFFu + ((u >> 16) & 1u)) >> 16;
}
__device__ __forceinline__ float bf2f(unsigned short h) {
    return __uint_as_float(((unsigned)h) << 16);
}

// K1: hidden(bf16) = x @ W, s1 = a[0:64]·h, s2 = a[64:128]·h.
// 256 blocks x 256 threads; 4 rows/block; W staged in LDS.
// Wave w owns k-quarter [w*32,w*32+32) for ALL 4 rows (W-element reuse:
// 32 Wl b32 + 32 xs b128 per thread vs r8's 160) -> 4-way partial combine.
__global__ __launch_bounds__(256) void k_hidden(
        const float* __restrict__ x, const float* __restrict__ W,
        const float* __restrict__ a,
        unsigned short* __restrict__ hbf, float* __restrict__ s1,
        float* __restrict__ s2) {
    const int row0 = blockIdx.x * 4;       // flat row b*GN+n, 0..1023
    const int tid = threadIdx.x;
    const int lane = tid & 63;
    const int w = tid >> 6;                // k-quarter 0..3
    __shared__ float Wl[INCH * GD];        // 32 KB
    __shared__ float xs[4][INCH];          // 2 KB
    __shared__ float hp[4][4][GD];         // 4 KB partials [kq][row][d]

    const float4* W4 = (const float4*)W;
    float4* Wl4 = (float4*)Wl;
    #pragma unroll
    for (int t = 0; t < 8; ++t) Wl4[tid + t * 256] = W4[tid + t * 256];
    if (tid < 4 * INCH / 4)
        ((float4*)xs)[tid] = ((const float4*)(x + (size_t)row0 * INCH))[tid];
    const float a1 = a[lane], a2 = a[GD + lane];
    __syncthreads();

    const int d = lane;
    const int k0 = w * 32;
    float h0 = 0.f, h1 = 0.f, h2 = 0.f, h3 = 0.f;
    #pragma unroll
    for (int k = 0; k < 32; ++k) {
        const float wv = Wl[(k0 + k) * GD + d];     // read once, used 4x
        h0 = fmaf(xs[0][k0 + k], wv, h0);
        h1 = fmaf(xs[1][k0 + k], wv, h1);
        h2 = fmaf(xs[2][k0 + k], wv, h2);
        h3 = fmaf(xs[3][k0 + k], wv, h3);
    }
    hp[w][0][d] = h0; hp[w][1][d] = h1; hp[w][2][d] = h2; hp[w][3][d] = h3;
    __syncthreads();

    {
        const int r = tid >> 6;                     // wave r owns row r
        const float h = hp[0][r][d] + hp[1][r][d] + hp[2][r][d] + hp[3][r][d];
        hbf[(size_t)(row0 + r) * GD + d] = (unsigned short)f2bf(h);
        float p1 = a1 * h, p2 = a2 * h;
        #pragma unroll
        for (int off = 32; off > 0; off >>= 1) {
            p1 += __shfl_xor(p1, off, 64);
            p2 += __shfl_xor(p2, off, 64);
        }
        if (d == 0) { s1[row0 + r] = p1; s2[row0 + r] = p2; }
    }
}

// K2 (byte-identical to r8's validated version): per (b,i): closed-form logits
// -> masked leaky-relu -> softmax (normalized weights in LDS) -> PV + bias.
//   i < 256 : pre(j) = (s1+s2)[2i + (j>=256)]
//   i >= 256: pre(j) = s1[2*(j%256)] + s2[2*(j%256)+1]   (period 4 in seg)
// PV hbf loads preissued before the softmax barrier (T14); lane owns d-pair,
// half-wave owns j parity, shfl_xor(32) merge.
__global__ __launch_bounds__(512) void k_attn(
        const int* __restrict__ adj, const unsigned short* __restrict__ hbf,
        const float* __restrict__ s1, const float* __restrict__ s2,
        const float* __restrict__ bias, float* __restrict__ out) {
    const int blk = blockIdx.x;
    const int b = blk >> 7;
    const int i0 = (blk & 127) * TI;
    const int tid = threadIdx.x;
    const int lane = tid & 63;
    const int w = tid >> 6;                // 0..7
    const int ld = lane & 31;              // d-pair index
    const int lh = lane >> 5;              // j parity

    __shared__ float plf[GN * TI];         // 8 KB, transposed+normalized: plf[j*4+row]
    __shared__ float red[8 * TI * GD];     // 8 KB

    // ---- preissue PV loads (independent of softmax) ----
    const unsigned short* hbg = hbf + (size_t)b * GN * GD;
    const int j0 = w * 64;
    unsigned int hv[32];                   // ushort2 h[j0+2*jj+lh][2*ld..2*ld+1]
    #pragma unroll
    for (int jj = 0; jj < 32; ++jj)
        hv[jj] = *((const unsigned int*)(hbg + (size_t)(j0 + 2 * jj + lh) * GD + 2 * ld));

    const float* s1b = s1 + b * GN;
    const float* s2b = s2 + b * GN;

    if (w < TI) {
        const int i = i0 + w;
        const int* adjw = adj + ((size_t)b * GN + i) * GN;
        float v[8];
        if (i < 256) {
            float c0 = s1b[2 * i] + s2b[2 * i];
            float c1 = s1b[2 * i + 1] + s2b[2 * i + 1];
            c0 = c0 >= 0.f ? c0 : ALPHA * c0;
            c1 = c1 >= 0.f ? c1 : ALPHA * c1;
            #pragma unroll
            for (int seg = 0; seg < 8; ++seg)
                v[seg] = adjw[seg * 64 + lane] > 0 ? (seg < 4 ? c0 : c1) : NEG_INF_F;
        } else {
            float pre4[4];
            #pragma unroll
            for (int sg = 0; sg < 4; ++sg) {         // m has period 4 in seg
                const int m = (sg * 64 + lane) & 255;
                float pre = s1b[2 * m] + s2b[2 * m + 1];
                pre4[sg] = pre >= 0.f ? pre : ALPHA * pre;
            }
            #pragma unroll
            for (int seg = 0; seg < 8; ++seg)
                v[seg] = adjw[seg * 64 + lane] > 0 ? pre4[seg & 3] : NEG_INF_F;
        }
        float mx = v[0];
        #pragma unroll
        for (int seg = 1; seg < 8; ++seg) mx = fmaxf(mx, v[seg]);
        #pragma unroll
        for (int off = 32; off > 0; off >>= 1) mx = fmaxf(mx, __shfl_xor(mx, off, 64));
        float e[8], s = 0.f;
        #pragma unroll
        for (int seg = 0; seg < 8; ++seg) {
            e[seg] = __expf(v[seg] - mx);
            s += e[seg];
        }
        #pragma unroll
        for (int off = 32; off > 0; off >>= 1) s += __shfl_xor(s, off, 64);
        const float inv = 1.f / s;
        #pragma unroll
        for (int seg = 0; seg < 8; ++seg)
            plf[(seg * 64 + lane) * TI + w] = e[seg] * inv;   // pre-normalized
    }
    __syncthreads();

    // ---- PV (pure LDS+VALU; loads already in hv) ----
    float a00 = 0.f, a01 = 0.f, a10 = 0.f, a11 = 0.f;
    float a20 = 0.f, a21 = 0.f, a30 = 0.f, a31 = 0.f;
    #pragma unroll 8
    for (int jj = 0; jj < 32; ++jj) {
        const int j = j0 + 2 * jj + lh;
        const float4 q = *((const float4*)(plf + j * TI));  // 2-addr broadcast
        const float h0 = bf2f((unsigned short)(hv[jj] & 0xFFFFu));
        const float h1 = bf2f((unsigned short)(hv[jj] >> 16));
        a00 = fmaf(q.x, h0, a00); a01 = fmaf(q.x, h1, a01);
        a10 = fmaf(q.y, h0, a10); a11 = fmaf(q.y, h1, a11);
        a20 = fmaf(q.z, h0, a20); a21 = fmaf(q.z, h1, a21);
        a30 = fmaf(q.w, h0, a30); a31 = fmaf(q.w, h1, a31);
    }
    // merge j-parity halves (lane <-> lane+32 hold same d-pair)
    a00 += __shfl_xor(a00, 32, 64); a01 += __shfl_xor(a01, 32, 64);
    a10 += __shfl_xor(a10, 32, 64); a11 += __shfl_xor(a11, 32, 64);
    a20 += __shfl_xor(a20, 32, 64); a21 += __shfl_xor(a21, 32, 64);
    a30 += __shfl_xor(a30, 32, 64); a31 += __shfl_xor(a31, 32, 64);
    if (lh == 0) {
        *(float2*)(red + (w * TI + 0) * GD + 2 * ld) = make_float2(a00, a01);
        *(float2*)(red + (w * TI + 1) * GD + 2 * ld) = make_float2(a10, a11);
        *(float2*)(red + (w * TI + 2) * GD + 2 * ld) = make_float2(a20, a21);
        *(float2*)(red + (w * TI + 3) * GD + 2 * ld) = make_float2(a30, a31);
    }
    __syncthreads();

    if (tid < TI * GD) {
        const int r = tid >> 6, d = tid & 63;
        float o = 0.f;
        #pragma unroll
        for (int ww = 0; ww < 8; ++ww) o += red[(ww * TI + r) * GD + d];
        o = o + bias[d];
        out[((size_t)b * GN + i0 + r) * GD + d] = o;
    }
}

extern "C" void kernel_launch(void* const* d_in, const int* in_sizes, int n_in,
                              void* d_out, int out_size, void* d_ws, size_t ws_size,
                              hipStream_t stream) {
    const float* x    = (const float*)d_in[0];
    const int*   adj  = (const int*)d_in[1];
    const float* W    = (const float*)d_in[2];
    const float* a    = (const float*)d_in[3];
    const float* bias = (const float*)d_in[4];
    float* out = (float*)d_out;

    // ws layout: hbf ushort[GB*GN*GD] | s1 f32[GB*GN] | s2 f32[GB*GN]
    unsigned short* hbf = (unsigned short*)d_ws;
    float* s1f = (float*)((char*)d_ws + GB * GN * GD * sizeof(unsigned short));
    float* s2f = s1f + GB * GN;

    k_hidden<<<GB * GN / 4, 256, 0, stream>>>(x, W, a, hbf, s1f, s2f);
    k_attn<<<GB * GN / TI, 512, 0, stream>>>(adj, hbf, s1f, s2f, bias, out);
}